// Round 5
// baseline (299.170 us; speedup 1.0000x reference)
//
#include <hip/hip_runtime.h>
#include <hip/hip_bf16.h>
#include <math.h>

#define LMAX 360
#define MMAX 361
#define NLAT 361
#define NLON 720
#define BC   32
#define MT   (BC*2*NLAT)   // 23104 rows
#define QT   722           // valid K (2*MMAX) for stage-2 GEMM
#define KP   736           // stage-2 padded K = 23*32
#define NP   768           // stage-2 padded N
#define BM   128
#define BN   128
#define BK   32

typedef __attribute__((ext_vector_type(8))) short short8;
typedef __attribute__((ext_vector_type(4))) float f32x4;

static __device__ __forceinline__ short f2bf(float v) {
    __hip_bfloat16 h = __float2bfloat16(v);
    return *reinterpret_cast<short*>(&h);
}

// ---------------------------------------------------------------------------
// prep_x: x (fp32, [bc][f][l][m][ri]) -> xT bf16 [m][src*32+bc][l], src=f*2+ri
// ---------------------------------------------------------------------------
__global__ __launch_bounds__(256) void sht_prep_x(
    const float* __restrict__ x, __hip_bfloat16* __restrict__ xT)
{
    const int m0 = blockIdx.x * 32;
    const int l0 = blockIdx.y * 64;
    const int bc = blockIdx.z >> 1, f = blockIdx.z & 1;
    __shared__ float2 tile[64][33];
    const float2* __restrict__ x2 = (const float2*)x;
    const int t = threadIdx.x;
    const int rm = t & 31, rl = t >> 5;

    #pragma unroll
    for (int r = 0; r < 8; ++r) {
        int l  = l0 + rl + r * 8;
        int mm = m0 + rm;
        float2 v = make_float2(0.f, 0.f);
        if (l < LMAX && mm < MMAX)
            v = x2[((size_t)(bc * 2 + f) * LMAX + l) * MMAX + mm];
        tile[rl + r * 8][rm] = v;
    }
    __syncthreads();

    const int tm = t >> 3, lg = t & 7;
    const int m = m0 + tm;
    if (m >= MMAX) return;
    const int lw = l0 + lg * 8;
    if (lw >= LMAX) return;          // 360 is granule-aligned (45*8)

    short8 re, im;
    #pragma unroll
    for (int e = 0; e < 8; ++e) {
        float2 v = tile[lg * 8 + e][tm];
        re[e] = f2bf(v.x);
        im[e] = f2bf(v.y);
    }
    size_t mb = (size_t)m * (128 * LMAX);
    *(short8*)((short*)xT + mb + (size_t)((f * 2 + 0) * 32 + bc) * LMAX + lw) = re;
    *(short8*)((short*)xT + mb + (size_t)((f * 2 + 1) * 32 + bc) * LMAX + lw) = im;
}

// ---------------------------------------------------------------------------
// gemm1: per-m MFMA GEMM.  D[k][combo] = sum_{l'} A[k][l'] * B[combo][l']
// K = 768 = two 384-padded halves (d0, d1); 12 steps of BKL=64.
// Grid (361, 4): each block owns 96 k-rows (more blocks/CU -> more TLP).
// A staging: task = (kd in [0,96), lo in [0,8)); 8 ALIGNED dword loads, each
// wavefront-coalesced (64 lanes -> 64 consecutive k); pack to short8; ONE
// swizzled ds_write_b128 per task.  B path unchanged (proven).
// ---------------------------------------------------------------------------
__global__ __launch_bounds__(256, 3) void sht_gemm1(
    const float* __restrict__ dpct, const __hip_bfloat16* __restrict__ xT,
    __hip_bfloat16* __restrict__ interQ)
{
    const int m  = blockIdx.x;
    const int K0 = blockIdx.y * 96;

    __shared__ __align__(16) char AlsB[96 * 128];    // [k][64l bf16], 128B rows
    __shared__ __align__(16) char BlsB[128 * 128];   // [c][64l bf16]

    const int t    = threadIdx.x;
    const int lane = t & 63;
    const int wave = t >> 6;
    const int wm = (wave >> 1) * 48;   // 3 M-frags
    const int wn = (wave & 1) * 64;    // 4 N-frags
    const int fr = lane & 15;
    const int lq = lane >> 4;

    // A staging: 768 tasks (kd, lo), 3 per thread
    int kdv[3], lov[3];
    #pragma unroll
    for (int it = 0; it < 3; ++it) {
        int task = it * 256 + t;
        kdv[it] = task % 96;
        lov[it] = task / 96;
    }
    // B staging: c = t>>1, granules g0B..g0B+3
    const int cB    = t >> 1;
    const int plane = cB >> 5, bcq = cB & 31;
    const int g0B   = (t & 1) * 4;

    const int            srcT[8] = {0, 1, 2, 3, 3, 2, 1, 0};
    const unsigned short sgnT[8] = {0, 0, 0x8000, 0x8000, 0x8000, 0, 0x8000, 0};

    f32x4 acc[3][4];
    const f32x4 zero = {0.f, 0.f, 0.f, 0.f};
    #pragma unroll
    for (int i = 0; i < 3; ++i)
        #pragma unroll
        for (int j = 0; j < 4; ++j) acc[i][j] = zero;

    float  apf[3][8];
    short8 bpf[4];

    auto loadA = [&](int ks) {
        int p = ks / 6, l0 = (ks % 6) * 64;
        #pragma unroll
        for (int it = 0; it < 3; ++it) {
            int kg = K0 + kdv[it];
            bool kval = (kg <= 360);
            int lb = l0 + lov[it] * 8;
            bool lval = (lb < LMAX);       // granule-aligned: fully valid or not
            const float* src = dpct +
                (((size_t)p * MMAX + m) * LMAX + lb) * (size_t)NLAT + kg;
            #pragma unroll
            for (int e = 0; e < 8; ++e) {
                apf[it][e] = (kval && lval) ? src[(size_t)e * NLAT] : 0.f;
            }
        }
    };

    auto loadB = [&](int ks) {
        int p = ks / 6, l0 = (ks % 6) * 64;
        int src = srcT[p * 4 + plane];
        short sg = (short)sgnT[p * 4 + plane];
        const short* bbase = (const short*)xT + (size_t)m * (128 * LMAX) +
                             (size_t)(src * 32 + bcq) * LMAX;
        #pragma unroll
        for (int i = 0; i < 4; ++i) {
            int g   = g0B + i;
            int lg2 = l0 + g * 8;
            short8 v;
            if (lg2 < LMAX) {
                v = *(const short8*)(bbase + lg2);
                #pragma unroll
                for (int e = 0; e < 8; ++e) v[e] ^= sg;
            } else {
                #pragma unroll
                for (int e = 0; e < 8; ++e) v[e] = 0;
            }
            bpf[i] = v;
        }
    };

    loadA(0);
    loadB(0);

    for (int ks = 0; ks < 12; ++ks) {
        __syncthreads();

        // A: pack 8 l-values -> one swizzled b128 write per task
        #pragma unroll
        for (int it = 0; it < 3; ++it) {
            short8 w;
            #pragma unroll
            for (int e = 0; e < 8; ++e) w[e] = f2bf(apf[it][e]);
            int kd = kdv[it], lo = lov[it];
            *(short8*)(AlsB + kd * 128 + ((lo ^ (kd & 7)) << 4)) = w;
        }
        // B: full-granule b128 writes
        #pragma unroll
        for (int i = 0; i < 4; ++i) {
            int g = g0B + i;
            *(short8*)(BlsB + cB * 128 + ((g ^ (cB & 7)) << 4)) = bpf[i];
        }
        __syncthreads();

        if (ks < 11) { loadA(ks + 1); loadB(ks + 1); }

        #pragma unroll
        for (int kk = 0; kk < 2; ++kk) {
            short8 af[3], bg[4];
            const int g = kk * 4 + lq;
            #pragma unroll
            for (int mi = 0; mi < 3; ++mi) {
                int k = wm + mi * 16 + fr;
                af[mi] = *(const short8*)(AlsB + k * 128 + ((g ^ (k & 7)) << 4));
            }
            #pragma unroll
            for (int ni = 0; ni < 4; ++ni) {
                int c = wn + ni * 16 + fr;
                bg[ni] = *(const short8*)(BlsB + c * 128 + ((g ^ (c & 7)) << 4));
            }
            #pragma unroll
            for (int mi = 0; mi < 3; ++mi)
                #pragma unroll
                for (int ni = 0; ni < 4; ++ni)
                    acc[mi][ni] = __builtin_amdgcn_mfma_f32_16x16x32_bf16(
                        af[mi], bg[ni], acc[mi][ni], 0, 0, 0);
        }
    }

    // store: k = K0 + wm + mi*16 + lq*4 + r ; combo c = wn + ni*16 + fr
    #pragma unroll
    for (int mi = 0; mi < 3; ++mi) {
        int kr = K0 + wm + mi * 16 + lq * 4;
        #pragma unroll
        for (int ni = 0; ni < 4; ++ni) {
            int c = wn + ni * 16 + fr;
            int pl = c >> 5, bc = c & 31;
            int ri = pl & 1, tt = pl >> 1;
            size_t qb = (size_t)(2 * m + ri) * MT + (size_t)(bc * 2 + tt) * NLAT;
            #pragma unroll
            for (int r = 0; r < 4; ++r) {
                int k = kr + r;
                if (k < NLAT)
                    interQ[qb + k] = __float2bfloat16(acc[mi][ni][r]);
            }
        }
    }
}

// ---------------------------------------------------------------------------
// Transpose interQ [722][23104] -> interT [23104][736] (zero K-pad)
// ---------------------------------------------------------------------------
__global__ __launch_bounds__(256) void sht_transpose(
    const __hip_bfloat16* __restrict__ inQ, __hip_bfloat16* __restrict__ outT)
{
    __shared__ __hip_bfloat16 tile[64][65];
    const int R0 = blockIdx.x * 64;
    const int q0 = blockIdx.y * 64;
    const int tx = threadIdx.x & 63;
    const int ty = threadIdx.x >> 6;
    const __hip_bfloat16 zv = __float2bfloat16(0.f);

    for (int qq = ty; qq < 64; qq += 4) {
        int q = q0 + qq;
        tile[qq][tx] = (q < QT) ? inQ[(size_t)q * MT + R0 + tx] : zv;
    }
    __syncthreads();
    if (q0 + tx < KP) {
        for (int rr = ty; rr < 64; rr += 4) {
            outT[(size_t)(R0 + rr) * KP + q0 + tx] = tile[tx][rr];
        }
    }
}

// ---------------------------------------------------------------------------
// W table [NP=768][KP=736] bf16
// ---------------------------------------------------------------------------
__global__ __launch_bounds__(256) void sht_make_w(__hip_bfloat16* __restrict__ W)
{
    const int idx = blockIdx.x * 256 + threadIdx.x;
    const int j = idx / KP;
    const int q = idx % KP;
    float v = 0.f;
    if (j < NLON && q < QT) {
        int m = q >> 1;
        float coef = (m == 0 || m == 360) ? 1.f : 2.f;
        int ph = (m * j) % 720;
        float ang = (float)ph * (float)(2.0 * M_PI / 720.0);
        float s, c;
        __sincosf(ang, &s, &c);
        v = (q & 1) ? (-coef * s) : (coef * c);
    }
    W[idx] = __float2bfloat16(v);
}

// ---------------------------------------------------------------------------
// Stage 2 GEMM (unchanged, proven): out[R][j] = sum_q interT[R][q] * W[j][q]
// ---------------------------------------------------------------------------
__global__ __launch_bounds__(256) void sht_gemm(
    const __hip_bfloat16* __restrict__ A,   // [MT][KP]
    const __hip_bfloat16* __restrict__ W,   // [NP][KP]
    float* __restrict__ out)                // [MT][NLON]
{
    __shared__ __align__(16) __hip_bfloat16 As[BM * BK];
    __shared__ __align__(16) __hip_bfloat16 Bs[BN * BK];
    const int t  = threadIdx.x;
    const int R0 = blockIdx.x * BM;
    const int J0 = blockIdx.y * BN;

    const int rowA = t >> 2;
    const int kc   = (t & 3) * 8;
    const int gr0  = min(R0 + rowA,      MT - 1);
    const int gr1  = min(R0 + rowA + 64, MT - 1);
    const __hip_bfloat16* pa0 = A + (size_t)gr0 * KP + kc;
    const __hip_bfloat16* pa1 = A + (size_t)gr1 * KP + kc;
    const __hip_bfloat16* pb0 = W + (size_t)(J0 + rowA) * KP + kc;
    const __hip_bfloat16* pb1 = W + (size_t)(J0 + rowA + 64) * KP + kc;

    const int lane = t & 63;
    const int wave = t >> 6;
    const int wm = (wave >> 1) * 64;
    const int wn = (wave & 1) * 64;
    const int fr = lane & 15;
    const int kg = (lane >> 4) * 8;

    f32x4 acc[4][4];
    const f32x4 zero = {0.f, 0.f, 0.f, 0.f};
    #pragma unroll
    for (int i = 0; i < 4; ++i)
        #pragma unroll
        for (int j = 0; j < 4; ++j) acc[i][j] = zero;

    short8 va0 = *(const short8*)pa0;
    short8 va1 = *(const short8*)pa1;
    short8 vb0 = *(const short8*)pb0;
    short8 vb1 = *(const short8*)pb1;

    for (int kt = 0; kt < KP / BK; ++kt) {
        __syncthreads();
        *(short8*)&As[t * 8]        = va0;
        *(short8*)&As[t * 8 + 2048] = va1;
        *(short8*)&Bs[t * 8]        = vb0;
        *(short8*)&Bs[t * 8 + 2048] = vb1;
        __syncthreads();

        if (kt + 1 < KP / BK) {
            const int ko = (kt + 1) * BK;
            va0 = *(const short8*)(pa0 + ko);
            va1 = *(const short8*)(pa1 + ko);
            vb0 = *(const short8*)(pb0 + ko);
            vb1 = *(const short8*)(pb1 + ko);
        }

        short8 af[4], bg[4];
        #pragma unroll
        for (int i = 0; i < 4; ++i)
            af[i] = *(const short8*)&As[(wm + i * 16 + fr) * BK + kg];
        #pragma unroll
        for (int i = 0; i < 4; ++i)
            bg[i] = *(const short8*)&Bs[(wn + i * 16 + fr) * BK + kg];

        #pragma unroll
        for (int mi = 0; mi < 4; ++mi)
            #pragma unroll
            for (int ni = 0; ni < 4; ++ni)
                acc[mi][ni] = __builtin_amdgcn_mfma_f32_16x16x32_bf16(
                    af[mi], bg[ni], acc[mi][ni], 0, 0, 0);
    }

    const int orow = (lane >> 4) * 4;
    #pragma unroll
    for (int mi = 0; mi < 4; ++mi) {
        #pragma unroll
        for (int ni = 0; ni < 4; ++ni) {
            #pragma unroll
            for (int r = 0; r < 4; ++r) {
                int row = R0 + wm + mi * 16 + orow + r;
                int col = J0 + wn + ni * 16 + fr;
                if (row < MT && col < NLON)
                    out[(size_t)row * NLON + col] = acc[mi][ni][r];
            }
        }
    }
}

// ---------------------------------------------------------------------------
// Workspace layout (total 67,371,264 B — proven available):
//   region A [0, 34,009,088):  xT (33,269,760 B)  then interT (34,009,088 B)
//   region B [34,009,088, 67,371,264):  interQ (33,362,176 B) then W
// ---------------------------------------------------------------------------
extern "C" void kernel_launch(void* const* d_in, const int* in_sizes, int n_in,
                              void* d_out, int out_size, void* d_ws, size_t ws_size,
                              hipStream_t stream)
{
    const float* x    = (const float*)d_in[0];
    const float* dpct = (const float*)d_in[1];
    float* out        = (float*)d_out;

    char* ws = (char*)d_ws;
    __hip_bfloat16* xT     = (__hip_bfloat16*)ws;
    __hip_bfloat16* interT = (__hip_bfloat16*)ws;
    __hip_bfloat16* interQ = (__hip_bfloat16*)(ws + 34009088);
    __hip_bfloat16* Wt     = (__hip_bfloat16*)(ws + 34009088);

    dim3 gp(12, 6, 64);
    sht_prep_x<<<gp, 256, 0, stream>>>(x, xT);

    dim3 g1(MMAX, 4);
    sht_gemm1<<<g1, 256, 0, stream>>>(dpct, xT, interQ);

    dim3 gt(MT / 64, 12);
    sht_transpose<<<gt, 256, 0, stream>>>(interQ, interT);

    sht_make_w<<<(NP * KP) / 256, 256, 0, stream>>>(Wt);

    dim3 gg((MT + BM - 1) / BM, NP / BN);
    sht_gemm<<<gg, 256, 0, stream>>>(interT, Wt, out);
}

// Round 6
// 285.708 us; speedup vs baseline: 1.0471x; 1.0471x over previous
//
#include <hip/hip_runtime.h>
#include <hip/hip_bf16.h>
#include <math.h>

#define LMAX 360
#define MMAX 361
#define NLAT 361
#define NLON 720
#define BC   32
#define MT   (BC*2*NLAT)   // 23104 rows
#define QT   722           // valid K (2*MMAX) for stage-2 GEMM
#define KP   736           // stage-2 padded K = 23*32
#define NP   768           // stage-2 padded N
#define BM   128
#define BN   128
#define BK   32

typedef __attribute__((ext_vector_type(8))) short short8;
typedef __attribute__((ext_vector_type(4))) short short4v;
typedef __attribute__((ext_vector_type(4))) float f32x4;

static __device__ __forceinline__ short f2bf(float v) {
    __hip_bfloat16 h = __float2bfloat16(v);
    return *reinterpret_cast<short*>(&h);
}

// ---------------------------------------------------------------------------
// prep_x: x (fp32, [bc][f][l][m][ri]) -> xT bf16 [m][src*32+bc][l], src=f*2+ri
// ---------------------------------------------------------------------------
__global__ __launch_bounds__(256) void sht_prep_x(
    const float* __restrict__ x, __hip_bfloat16* __restrict__ xT)
{
    const int m0 = blockIdx.x * 32;
    const int l0 = blockIdx.y * 64;
    const int bc = blockIdx.z >> 1, f = blockIdx.z & 1;
    __shared__ float2 tile[64][33];
    const float2* __restrict__ x2 = (const float2*)x;
    const int t = threadIdx.x;
    const int rm = t & 31, rl = t >> 5;

    #pragma unroll
    for (int r = 0; r < 8; ++r) {
        int l  = l0 + rl + r * 8;
        int mm = m0 + rm;
        float2 v = make_float2(0.f, 0.f);
        if (l < LMAX && mm < MMAX)
            v = x2[((size_t)(bc * 2 + f) * LMAX + l) * MMAX + mm];
        tile[rl + r * 8][rm] = v;
    }
    __syncthreads();

    const int tm = t >> 3, lg = t & 7;
    const int m = m0 + tm;
    if (m >= MMAX) return;
    const int lw = l0 + lg * 8;
    if (lw >= LMAX) return;          // 360 is granule-aligned (45*8)

    short8 re, im;
    #pragma unroll
    for (int e = 0; e < 8; ++e) {
        float2 v = tile[lg * 8 + e][tm];
        re[e] = f2bf(v.x);
        im[e] = f2bf(v.y);
    }
    size_t mb = (size_t)m * (128 * LMAX);
    *(short8*)((short*)xT + mb + (size_t)((f * 2 + 0) * 32 + bc) * LMAX + lw) = re;
    *(short8*)((short*)xT + mb + (size_t)((f * 2 + 1) * 32 + bc) * LMAX + lw) = im;
}

// ---------------------------------------------------------------------------
// gemm1 v3: per-m MFMA GEMM, wave-autonomous A path.
//   D[k][combo] = sum_{l'} A[k][l'] * B[combo][l'], K=768 (two 384-pad halves)
// Block (m, kblk of 192): 4 waves; wave owns 48 k-rows x all 128 combos
// (3 M-frags x 8 N-frags). A staged per-wave into PRIVATE LDS (no barrier,
// lgkmcnt only): 12 float4 dpct loads -> 4x4 reg transpose -> swizzled
// ds_write_b64 ([48][144B] rows, granule XOR (k&14), pair-preserving).
// B (16KB) shared + double-buffered: ONE barrier per K-step, gating only a
// 1-deep B prefetch. 12 steps of 64 l.
// ---------------------------------------------------------------------------
__global__ __launch_bounds__(256, 2) void sht_gemm1(
    const float* __restrict__ dpct, const __hip_bfloat16* __restrict__ xT,
    __hip_bfloat16* __restrict__ interQ)
{
    const int m  = blockIdx.x;
    const int K0 = blockIdx.y * 192;

    __shared__ __align__(16) char Als[4 * 48 * 144];   // per-wave A, 27648 B
    __shared__ __align__(16) char Bls[2][128 * 128];   // B dbuf, 32768 B

    const int t    = threadIdx.x;
    const int lane = t & 63;
    const int wave = t >> 6;
    const int wk   = K0 + wave * 48;      // this wave's global k base
    char* Aw = Als + wave * (48 * 144);

    const int fr = lane & 15;
    const int lq = lane >> 4;

    // A staging tasks: 192 (kq,lb) tasks per wave, 3 per lane
    int kqv[3], lbv[3];
    #pragma unroll
    for (int it = 0; it < 3; ++it) {
        int task = it * 64 + lane;
        kqv[it] = task % 12;     // k-quad within 48
        lbv[it] = task / 12;     // l-granule of 4 within 64
    }
    // B staging: row c = t>>1, 4 granules each
    const int cB    = t >> 1;
    const int plane = cB >> 5, bcq = cB & 31;
    const int g0B   = (t & 1) * 4;

    const int            srcT[8] = {0, 1, 2, 3, 3, 2, 1, 0};
    const unsigned short sgnT[8] = {0, 0, 0x8000, 0x8000, 0x8000, 0, 0x8000, 0};

    f32x4 acc[3][8];
    const f32x4 zero = {0.f, 0.f, 0.f, 0.f};
    #pragma unroll
    for (int i = 0; i < 3; ++i)
        #pragma unroll
        for (int j = 0; j < 8; ++j) acc[i][j] = zero;

    float4 apf[3][4];
    short8 bpf[4];

    auto loadA = [&](int p, int l0) {
        const size_t rowb = ((size_t)p * MMAX + m) * LMAX;
        #pragma unroll
        for (int it = 0; it < 3; ++it) {
            const int kg = wk + kqv[it] * 4;
            #pragma unroll
            for (int j = 0; j < 4; ++j) {
                int l = l0 + lbv[it] * 4 + j;
                float4 v = make_float4(0.f, 0.f, 0.f, 0.f);
                if (l < LMAX) {
                    const float* src = dpct + (rowb + l) * (size_t)NLAT + kg;
                    if (kg + 3 <= 360) {
                        v = *(const float4*)src;
                    } else if (kg <= 360) {
                        v.x = src[0];
                        if (kg + 1 <= 360) v.y = src[1];
                        if (kg + 2 <= 360) v.z = src[2];
                    }
                }
                apf[it][j] = v;
            }
        }
    };

    auto loadB = [&](int p, int l0) {
        int src = srcT[p * 4 + plane];
        short sg = (short)sgnT[p * 4 + plane];
        const short* bbase = (const short*)xT + (size_t)m * (128 * LMAX) +
                             (size_t)(src * 32 + bcq) * LMAX;
        #pragma unroll
        for (int i = 0; i < 4; ++i) {
            int g   = g0B + i;
            int lg2 = l0 + g * 8;
            short8 v;
            if (lg2 < LMAX) {
                v = *(const short8*)(bbase + lg2);
                #pragma unroll
                for (int e = 0; e < 8; ++e) v[e] ^= sg;
            } else {
                #pragma unroll
                for (int e = 0; e < 8; ++e) v[e] = 0;
            }
            bpf[i] = v;
        }
    };

    auto writeA = [&]() {
        #pragma unroll
        for (int it = 0; it < 3; ++it) {
            const int lb = lbv[it];
#define WRITE_A_ROW(JJ, E0, E1, E2, E3)                                        \
            {                                                                  \
                int kl = kqv[it] * 4 + JJ;                                     \
                short4v w;                                                     \
                w[0] = f2bf(E0); w[1] = f2bf(E1);                              \
                w[2] = f2bf(E2); w[3] = f2bf(E3);                              \
                *(short4v*)(Aw + kl * 144 + ((lb ^ (kl & 14)) << 3)) = w;      \
            }
            WRITE_A_ROW(0, apf[it][0].x, apf[it][1].x, apf[it][2].x, apf[it][3].x)
            WRITE_A_ROW(1, apf[it][0].y, apf[it][1].y, apf[it][2].y, apf[it][3].y)
            WRITE_A_ROW(2, apf[it][0].z, apf[it][1].z, apf[it][2].z, apf[it][3].z)
            WRITE_A_ROW(3, apf[it][0].w, apf[it][1].w, apf[it][2].w, apf[it][3].w)
#undef WRITE_A_ROW
        }
    };

    auto writeB = [&](char* Bb) {
        #pragma unroll
        for (int i = 0; i < 4; ++i) {
            int g = g0B + i;
            *(short8*)(Bb + cB * 128 + ((g ^ (cB & 7)) << 4)) = bpf[i];
        }
    };

    // prologue
    loadB(0, 0);
    loadA(0, 0);
    writeB(&Bls[0][0]);
    __syncthreads();

    #pragma unroll 1
    for (int s = 0; s < 12; ++s) {
        const int pn  = (s + 1 >= 6) ? 1 : 0;
        const int l0n = ((s + 1) % 6) * 64;

        if (s < 11) loadB(pn, l0n);        // issue next-B global loads
        writeA();                          // A(s): reg -> private LDS
        if (s < 11) loadA(pn, l0n);        // issue next-A global loads

        asm volatile("s_waitcnt lgkmcnt(0)" ::: "memory");
        __builtin_amdgcn_sched_barrier(0);

        const char* Bb = &Bls[s & 1][0];
        #pragma unroll
        for (int kk = 0; kk < 2; ++kk) {
            short8 af[3], bg[8];
            const int g8  = (kk * 4 + lq) * 2;   // even 8B-granule index
            const int g16 = kk * 4 + lq;         // 16B granule index
            #pragma unroll
            for (int mi = 0; mi < 3; ++mi) {
                int kl = mi * 16 + fr;
                af[mi] = *(const short8*)(Aw + kl * 144 + ((g8 ^ (kl & 14)) << 3));
            }
            #pragma unroll
            for (int ni = 0; ni < 8; ++ni) {
                int c = ni * 16 + fr;
                bg[ni] = *(const short8*)(Bb + c * 128 + ((g16 ^ (c & 7)) << 4));
            }
            #pragma unroll
            for (int mi = 0; mi < 3; ++mi)
                #pragma unroll
                for (int ni = 0; ni < 8; ++ni)
                    acc[mi][ni] = __builtin_amdgcn_mfma_f32_16x16x32_bf16(
                        af[mi], bg[ni], acc[mi][ni], 0, 0, 0);
        }

        if (s < 11) {
            writeB(&Bls[(s + 1) & 1][0]);  // other buffer: safe vs compute(s)
            __syncthreads();
        }
    }

    // store: k = wk + mi*16 + lq*4 + r ; combo c = ni*16 + fr
    #pragma unroll
    for (int mi = 0; mi < 3; ++mi) {
        int kr = wk + mi * 16 + lq * 4;
        #pragma unroll
        for (int ni = 0; ni < 8; ++ni) {
            int c = ni * 16 + fr;
            int pl = c >> 5, bc = c & 31;
            int ri = pl & 1, tt = pl >> 1;
            size_t qb = (size_t)(2 * m + ri) * MT + (size_t)(bc * 2 + tt) * NLAT;
            #pragma unroll
            for (int r = 0; r < 4; ++r) {
                int k = kr + r;
                if (k < NLAT)
                    interQ[qb + k] = __float2bfloat16(acc[mi][ni][r]);
            }
        }
    }
}

// ---------------------------------------------------------------------------
// Transpose interQ [722][23104] -> interT [23104][736] (zero K-pad)
// ---------------------------------------------------------------------------
__global__ __launch_bounds__(256) void sht_transpose(
    const __hip_bfloat16* __restrict__ inQ, __hip_bfloat16* __restrict__ outT)
{
    __shared__ __hip_bfloat16 tile[64][65];
    const int R0 = blockIdx.x * 64;
    const int q0 = blockIdx.y * 64;
    const int tx = threadIdx.x & 63;
    const int ty = threadIdx.x >> 6;
    const __hip_bfloat16 zv = __float2bfloat16(0.f);

    for (int qq = ty; qq < 64; qq += 4) {
        int q = q0 + qq;
        tile[qq][tx] = (q < QT) ? inQ[(size_t)q * MT + R0 + tx] : zv;
    }
    __syncthreads();
    if (q0 + tx < KP) {
        for (int rr = ty; rr < 64; rr += 4) {
            outT[(size_t)(R0 + rr) * KP + q0 + tx] = tile[tx][rr];
        }
    }
}

// ---------------------------------------------------------------------------
// W table [NP=768][KP=736] bf16
// ---------------------------------------------------------------------------
__global__ __launch_bounds__(256) void sht_make_w(__hip_bfloat16* __restrict__ W)
{
    const int idx = blockIdx.x * 256 + threadIdx.x;
    const int j = idx / KP;
    const int q = idx % KP;
    float v = 0.f;
    if (j < NLON && q < QT) {
        int m = q >> 1;
        float coef = (m == 0 || m == 360) ? 1.f : 2.f;
        int ph = (m * j) % 720;
        float ang = (float)ph * (float)(2.0 * M_PI / 720.0);
        float s, c;
        __sincosf(ang, &s, &c);
        v = (q & 1) ? (-coef * s) : (coef * c);
    }
    W[idx] = __float2bfloat16(v);
}

// ---------------------------------------------------------------------------
// Stage 2 GEMM (unchanged, proven): out[R][j] = sum_q interT[R][q] * W[j][q]
// ---------------------------------------------------------------------------
__global__ __launch_bounds__(256) void sht_gemm(
    const __hip_bfloat16* __restrict__ A,   // [MT][KP]
    const __hip_bfloat16* __restrict__ W,   // [NP][KP]
    float* __restrict__ out)                // [MT][NLON]
{
    __shared__ __align__(16) __hip_bfloat16 As[BM * BK];
    __shared__ __align__(16) __hip_bfloat16 Bs[BN * BK];
    const int t  = threadIdx.x;
    const int R0 = blockIdx.x * BM;
    const int J0 = blockIdx.y * BN;

    const int rowA = t >> 2;
    const int kc   = (t & 3) * 8;
    const int gr0  = min(R0 + rowA,      MT - 1);
    const int gr1  = min(R0 + rowA + 64, MT - 1);
    const __hip_bfloat16* pa0 = A + (size_t)gr0 * KP + kc;
    const __hip_bfloat16* pa1 = A + (size_t)gr1 * KP + kc;
    const __hip_bfloat16* pb0 = W + (size_t)(J0 + rowA) * KP + kc;
    const __hip_bfloat16* pb1 = W + (size_t)(J0 + rowA + 64) * KP + kc;

    const int lane = t & 63;
    const int wave = t >> 6;
    const int wm = (wave >> 1) * 64;
    const int wn = (wave & 1) * 64;
    const int fr = lane & 15;
    const int kg = (lane >> 4) * 8;

    f32x4 acc[4][4];
    const f32x4 zero = {0.f, 0.f, 0.f, 0.f};
    #pragma unroll
    for (int i = 0; i < 4; ++i)
        #pragma unroll
        for (int j = 0; j < 4; ++j) acc[i][j] = zero;

    short8 va0 = *(const short8*)pa0;
    short8 va1 = *(const short8*)pa1;
    short8 vb0 = *(const short8*)pb0;
    short8 vb1 = *(const short8*)pb1;

    for (int kt = 0; kt < KP / BK; ++kt) {
        __syncthreads();
        *(short8*)&As[t * 8]        = va0;
        *(short8*)&As[t * 8 + 2048] = va1;
        *(short8*)&Bs[t * 8]        = vb0;
        *(short8*)&Bs[t * 8 + 2048] = vb1;
        __syncthreads();

        if (kt + 1 < KP / BK) {
            const int ko = (kt + 1) * BK;
            va0 = *(const short8*)(pa0 + ko);
            va1 = *(const short8*)(pa1 + ko);
            vb0 = *(const short8*)(pb0 + ko);
            vb1 = *(const short8*)(pb1 + ko);
        }

        short8 af[4], bg[4];
        #pragma unroll
        for (int i = 0; i < 4; ++i)
            af[i] = *(const short8*)&As[(wm + i * 16 + fr) * BK + kg];
        #pragma unroll
        for (int i = 0; i < 4; ++i)
            bg[i] = *(const short8*)&Bs[(wn + i * 16 + fr) * BK + kg];

        #pragma unroll
        for (int mi = 0; mi < 4; ++mi)
            #pragma unroll
            for (int ni = 0; ni < 4; ++ni)
                acc[mi][ni] = __builtin_amdgcn_mfma_f32_16x16x32_bf16(
                    af[mi], bg[ni], acc[mi][ni], 0, 0, 0);
    }

    const int orow = (lane >> 4) * 4;
    #pragma unroll
    for (int mi = 0; mi < 4; ++mi) {
        #pragma unroll
        for (int ni = 0; ni < 4; ++ni) {
            #pragma unroll
            for (int r = 0; r < 4; ++r) {
                int row = R0 + wm + mi * 16 + orow + r;
                int col = J0 + wn + ni * 16 + fr;
                if (row < MT && col < NLON)
                    out[(size_t)row * NLON + col] = acc[mi][ni][r];
            }
        }
    }
}

// ---------------------------------------------------------------------------
// Workspace layout (total 67,371,264 B — proven available):
//   region A [0, 34,009,088):  xT (33,269,760 B)  then interT (34,009,088 B)
//   region B [34,009,088, 67,371,264):  interQ (33,362,176 B) then W
// ---------------------------------------------------------------------------
extern "C" void kernel_launch(void* const* d_in, const int* in_sizes, int n_in,
                              void* d_out, int out_size, void* d_ws, size_t ws_size,
                              hipStream_t stream)
{
    const float* x    = (const float*)d_in[0];
    const float* dpct = (const float*)d_in[1];
    float* out        = (float*)d_out;

    char* ws = (char*)d_ws;
    __hip_bfloat16* xT     = (__hip_bfloat16*)ws;
    __hip_bfloat16* interT = (__hip_bfloat16*)ws;
    __hip_bfloat16* interQ = (__hip_bfloat16*)(ws + 34009088);
    __hip_bfloat16* Wt     = (__hip_bfloat16*)(ws + 34009088);

    dim3 gp(12, 6, 64);
    sht_prep_x<<<gp, 256, 0, stream>>>(x, xT);

    dim3 g1(MMAX, 2);
    sht_gemm1<<<g1, 256, 0, stream>>>(dpct, xT, interQ);

    dim3 gt(MT / 64, 12);
    sht_transpose<<<gt, 256, 0, stream>>>(interQ, interT);

    sht_make_w<<<(NP * KP) / 256, 256, 0, stream>>>(Wt);

    dim3 gg((MT + BM - 1) / BM, NP / BN);
    sht_gemm<<<gg, 256, 0, stream>>>(interT, Wt, out);
}

// Round 8
// 273.584 us; speedup vs baseline: 1.0935x; 1.0443x over previous
//
#include <hip/hip_runtime.h>
#include <hip/hip_bf16.h>
#include <math.h>

#define LMAX 360
#define MMAX 361
#define NLAT 361
#define NLON 720
#define BC   32
#define MT   (BC*2*NLAT)   // 23104 rows
#define QT   722           // valid K (2*MMAX) for stage-2 GEMM
#define KP   736           // stage-2 padded K = 23*32
#define NP   768           // stage-2 padded N
#define BM   128
#define BN   128
#define BK   32

typedef __attribute__((ext_vector_type(8))) short short8;
typedef __attribute__((ext_vector_type(4))) float f32x4;

static __device__ __forceinline__ short f2bf(float v) {
    __hip_bfloat16 h = __float2bfloat16(v);
    return *reinterpret_cast<short*>(&h);
}

// ---------------------------------------------------------------------------
// prep_x: x (fp32, [bc][f][l][m][ri]) -> xT bf16 [m][src*32+bc][l], src=f*2+ri
// Loads are UNCONDITIONAL with clamped addresses (no select between issues);
// OOB data is never written out (write side is bounds-checked).
// ---------------------------------------------------------------------------
__global__ __launch_bounds__(256) void sht_prep_x(
    const float* __restrict__ x, __hip_bfloat16* __restrict__ xT)
{
    const int m0 = blockIdx.x * 32;
    const int l0 = blockIdx.y * 64;
    const int bc = blockIdx.z >> 1, f = blockIdx.z & 1;
    __shared__ float2 tile[64][33];
    const float2* __restrict__ x2 = (const float2*)x;
    const int t = threadIdx.x;
    const int rm = t & 31, rl = t >> 5;

    const int mm = min(m0 + rm, MMAX - 1);
    #pragma unroll
    for (int r = 0; r < 8; ++r) {
        int l = min(l0 + rl + r * 8, LMAX - 1);
        tile[rl + r * 8][rm] = x2[((size_t)(bc * 2 + f) * LMAX + l) * MMAX + mm];
    }
    __syncthreads();

    const int tm = t >> 3, lg = t & 7;
    const int m = m0 + tm;
    if (m >= MMAX) return;
    const int lw = l0 + lg * 8;
    if (lw >= LMAX) return;          // 360 is granule-aligned (45*8)

    short8 re, im;
    #pragma unroll
    for (int e = 0; e < 8; ++e) {
        float2 v = tile[lg * 8 + e][tm];
        re[e] = f2bf(v.x);
        im[e] = f2bf(v.y);
    }
    size_t mb = (size_t)m * (128 * LMAX);
    *(short8*)((short*)xT + mb + (size_t)((f * 2 + 0) * 32 + bc) * LMAX + lw) = re;
    *(short8*)((short*)xT + mb + (size_t)((f * 2 + 1) * 32 + bc) * LMAX + lw) = im;
}

// ---------------------------------------------------------------------------
// gemm1 (R4 structure, load-pipeline fixed): per-m MFMA GEMM.
//   D[k][combo] = sum_{l'} A[k][l'] * B[combo][l'], K = 768 (two 384 halves)
// Grid (361, 4): block owns 96 k-rows. 12 steps of 64 l.
// A staging: task (kd in [0,96), lo in [0,8)); 8 UNCONDITIONAL aligned dword
// loads at clamped addresses (wave-coalesced: 64 lanes -> consecutive k);
// validity/zeroing applied at LDS-write time (after all loads issued).
// k-clamped garbage rows (k>360) are finite and dropped at the store bound.
// B: xT short8 granules, clamped addresses; sign-XOR + zero at write time.
// LDS swizzle + fragment mappings identical to proven R4.
// ---------------------------------------------------------------------------
__global__ __launch_bounds__(256, 3) void sht_gemm1(
    const float* __restrict__ dpct, const __hip_bfloat16* __restrict__ xT,
    __hip_bfloat16* __restrict__ interQ)
{
    const int m  = blockIdx.x;
    const int K0 = blockIdx.y * 96;

    __shared__ __align__(16) char AlsB[96 * 128];    // [k][64l bf16], 128B rows
    __shared__ __align__(16) char BlsB[128 * 128];   // [c][64l bf16]

    const int t    = threadIdx.x;
    const int lane = t & 63;
    const int wave = t >> 6;
    const int wm = (wave >> 1) * 48;   // 3 M-frags
    const int wn = (wave & 1) * 64;    // 4 N-frags
    const int fr = lane & 15;
    const int lq = lane >> 4;

    // A staging: 768 tasks (kd, lo), 3 per thread
    int kdv[3], lov[3], kcl[3];
    #pragma unroll
    for (int it = 0; it < 3; ++it) {
        int task = it * 256 + t;
        kdv[it] = task % 96;
        lov[it] = task / 96;
        kcl[it] = min(K0 + kdv[it], 360);   // clamped k (garbage rows dropped)
    }
    // B staging: c = t>>1, granules g0B..g0B+3
    const int cB    = t >> 1;
    const int plane = cB >> 5, bcq = cB & 31;
    const int g0B   = (t & 1) * 4;

    const int            srcT[8] = {0, 1, 2, 3, 3, 2, 1, 0};
    const unsigned short sgnT[8] = {0, 0, 0x8000, 0x8000, 0x8000, 0, 0x8000, 0};

    f32x4 acc[3][4];
    const f32x4 zero = {0.f, 0.f, 0.f, 0.f};
    #pragma unroll
    for (int i = 0; i < 3; ++i)
        #pragma unroll
        for (int j = 0; j < 4; ++j) acc[i][j] = zero;

    float  apf[3][8];
    short8 bpf[4];
    bool   lvA[3], bvB[4];
    short  bsgn = 0;

    auto loadA = [&](int p, int l0) {
        const size_t rowb = ((size_t)p * MMAX + m) * LMAX;
        #pragma unroll
        for (int it = 0; it < 3; ++it) {
            int lb = l0 + lov[it] * 8;
            lvA[it] = (lb < LMAX);               // granule-aligned: all-or-none
            int lcl = lvA[it] ? lb : 0;
            const float* src = dpct + (rowb + lcl) * (size_t)NLAT + kcl[it];
            #pragma unroll
            for (int e = 0; e < 8; ++e)
                apf[it][e] = src[(size_t)e * NLAT];   // unconditional
        }
    };

    auto loadB = [&](int p, int l0) {
        int src = srcT[p * 4 + plane];
        bsgn = (short)sgnT[p * 4 + plane];
        const short* bbase = (const short*)xT + (size_t)m * (128 * LMAX) +
                             (size_t)(src * 32 + bcq) * LMAX;
        #pragma unroll
        for (int i = 0; i < 4; ++i) {
            int lg2 = l0 + (g0B + i) * 8;
            bvB[i] = (lg2 < LMAX);
            int lcl = bvB[i] ? lg2 : 0;
            bpf[i] = *(const short8*)(bbase + lcl);   // unconditional
        }
    };

    auto writeA = [&]() {
        #pragma unroll
        for (int it = 0; it < 3; ++it) {
            short8 w;
            #pragma unroll
            for (int e = 0; e < 8; ++e)
                w[e] = lvA[it] ? f2bf(apf[it][e]) : (short)0;
            int kd = kdv[it], lo = lov[it];
            *(short8*)(AlsB + kd * 128 + ((lo ^ (kd & 7)) << 4)) = w;
        }
    };

    auto writeB = [&]() {
        #pragma unroll
        for (int i = 0; i < 4; ++i) {
            short8 v = bpf[i];
            #pragma unroll
            for (int e = 0; e < 8; ++e) {
                short xe = (short)(v[e] ^ bsgn);
                v[e] = bvB[i] ? xe : (short)0;
            }
            int g = g0B + i;
            *(short8*)(BlsB + cB * 128 + ((g ^ (cB & 7)) << 4)) = v;
        }
    };

    loadA(0, 0);
    loadB(0, 0);

    #pragma unroll 1
    for (int s = 0; s < 12; ++s) {
        __syncthreads();          // previous step's LDS reads complete
        writeA();
        writeB();
        __syncthreads();

        if (s < 11) {
            const int pn  = (s + 1 >= 6) ? 1 : 0;
            const int l0n = ((s + 1) % 6) * 64;
            loadA(pn, l0n);
            loadB(pn, l0n);
        }

        #pragma unroll
        for (int kk = 0; kk < 2; ++kk) {
            short8 af[3], bg[4];
            const int g = kk * 4 + lq;
            #pragma unroll
            for (int mi = 0; mi < 3; ++mi) {
                int k = wm + mi * 16 + fr;
                af[mi] = *(const short8*)(AlsB + k * 128 + ((g ^ (k & 7)) << 4));
            }
            #pragma unroll
            for (int ni = 0; ni < 4; ++ni) {
                int c = wn + ni * 16 + fr;
                bg[ni] = *(const short8*)(BlsB + c * 128 + ((g ^ (c & 7)) << 4));
            }
            #pragma unroll
            for (int mi = 0; mi < 3; ++mi)
                #pragma unroll
                for (int ni = 0; ni < 4; ++ni)
                    acc[mi][ni] = __builtin_amdgcn_mfma_f32_16x16x32_bf16(
                        af[mi], bg[ni], acc[mi][ni], 0, 0, 0);
        }
    }

    // store: k = K0 + wm + mi*16 + lq*4 + r ; combo c = wn + ni*16 + fr
    #pragma unroll
    for (int mi = 0; mi < 3; ++mi) {
        int kr = K0 + wm + mi * 16 + lq * 4;
        #pragma unroll
        for (int ni = 0; ni < 4; ++ni) {
            int c = wn + ni * 16 + fr;
            int pl = c >> 5, bc = c & 31;
            int ri = pl & 1, tt = pl >> 1;
            size_t qb = (size_t)(2 * m + ri) * MT + (size_t)(bc * 2 + tt) * NLAT;
            #pragma unroll
            for (int r = 0; r < 4; ++r) {
                int k = kr + r;
                if (k < NLAT)
                    interQ[qb + k] = __float2bfloat16(acc[mi][ni][r]);
            }
        }
    }
}

// ---------------------------------------------------------------------------
// Transpose interQ [722][23104] -> interT [23104][736] (zero K-pad)
// ---------------------------------------------------------------------------
__global__ __launch_bounds__(256) void sht_transpose(
    const __hip_bfloat16* __restrict__ inQ, __hip_bfloat16* __restrict__ outT)
{
    __shared__ __hip_bfloat16 tile[64][65];
    const int R0 = blockIdx.x * 64;
    const int q0 = blockIdx.y * 64;
    const int tx = threadIdx.x & 63;
    const int ty = threadIdx.x >> 6;
    const __hip_bfloat16 zv = __float2bfloat16(0.f);

    for (int qq = ty; qq < 64; qq += 4) {
        int q = q0 + qq;
        tile[qq][tx] = (q < QT) ? inQ[(size_t)q * MT + R0 + tx] : zv;
    }
    __syncthreads();
    if (q0 + tx < KP) {
        for (int rr = ty; rr < 64; rr += 4) {
            outT[(size_t)(R0 + rr) * KP + q0 + tx] = tile[tx][rr];
        }
    }
}

// ---------------------------------------------------------------------------
// W table [NP=768][KP=736] bf16
// ---------------------------------------------------------------------------
__global__ __launch_bounds__(256) void sht_make_w(__hip_bfloat16* __restrict__ W)
{
    const int idx = blockIdx.x * 256 + threadIdx.x;
    const int j = idx / KP;
    const int q = idx % KP;
    float v = 0.f;
    if (j < NLON && q < QT) {
        int m = q >> 1;
        float coef = (m == 0 || m == 360) ? 1.f : 2.f;
        int ph = (m * j) % 720;
        float ang = (float)ph * (float)(2.0 * M_PI / 720.0);
        float s, c;
        __sincosf(ang, &s, &c);
        v = (q & 1) ? (-coef * s) : (coef * c);
    }
    W[idx] = __float2bfloat16(v);
}

// ---------------------------------------------------------------------------
// Stage 2 GEMM (unchanged, proven): out[R][j] = sum_q interT[R][q] * W[j][q]
// ---------------------------------------------------------------------------
__global__ __launch_bounds__(256) void sht_gemm(
    const __hip_bfloat16* __restrict__ A,   // [MT][KP]
    const __hip_bfloat16* __restrict__ W,   // [NP][KP]
    float* __restrict__ out)                // [MT][NLON]
{
    __shared__ __align__(16) __hip_bfloat16 As[BM * BK];
    __shared__ __align__(16) __hip_bfloat16 Bs[BN * BK];
    const int t  = threadIdx.x;
    const int R0 = blockIdx.x * BM;
    const int J0 = blockIdx.y * BN;

    const int rowA = t >> 2;
    const int kc   = (t & 3) * 8;
    const int gr0  = min(R0 + rowA,      MT - 1);
    const int gr1  = min(R0 + rowA + 64, MT - 1);
    const __hip_bfloat16* pa0 = A + (size_t)gr0 * KP + kc;
    const __hip_bfloat16* pa1 = A + (size_t)gr1 * KP + kc;
    const __hip_bfloat16* pb0 = W + (size_t)(J0 + rowA) * KP + kc;
    const __hip_bfloat16* pb1 = W + (size_t)(J0 + rowA + 64) * KP + kc;

    const int lane = t & 63;
    const int wave = t >> 6;
    const int wm = (wave >> 1) * 64;
    const int wn = (wave & 1) * 64;
    const int fr = lane & 15;
    const int kg = (lane >> 4) * 8;

    f32x4 acc[4][4];
    const f32x4 zero = {0.f, 0.f, 0.f, 0.f};
    #pragma unroll
    for (int i = 0; i < 4; ++i)
        #pragma unroll
        for (int j = 0; j < 4; ++j) acc[i][j] = zero;

    short8 va0 = *(const short8*)pa0;
    short8 va1 = *(const short8*)pa1;
    short8 vb0 = *(const short8*)pb0;
    short8 vb1 = *(const short8*)pb1;

    for (int kt = 0; kt < KP / BK; ++kt) {
        __syncthreads();
        *(short8*)&As[t * 8]        = va0;
        *(short8*)&As[t * 8 + 2048] = va1;
        *(short8*)&Bs[t * 8]        = vb0;
        *(short8*)&Bs[t * 8 + 2048] = vb1;
        __syncthreads();

        if (kt + 1 < KP / BK) {
            const int ko = (kt + 1) * BK;
            va0 = *(const short8*)(pa0 + ko);
            va1 = *(const short8*)(pa1 + ko);
            vb0 = *(const short8*)(pb0 + ko);
            vb1 = *(const short8*)(pb1 + ko);
        }

        short8 af[4], bg[4];
        #pragma unroll
        for (int i = 0; i < 4; ++i)
            af[i] = *(const short8*)&As[(wm + i * 16 + fr) * BK + kg];
        #pragma unroll
        for (int i = 0; i < 4; ++i)
            bg[i] = *(const short8*)&Bs[(wn + i * 16 + fr) * BK + kg];

        #pragma unroll
        for (int mi = 0; mi < 4; ++mi)
            #pragma unroll
            for (int ni = 0; ni < 4; ++ni)
                acc[mi][ni] = __builtin_amdgcn_mfma_f32_16x16x32_bf16(
                    af[mi], bg[ni], acc[mi][ni], 0, 0, 0);
    }

    const int orow = (lane >> 4) * 4;
    #pragma unroll
    for (int mi = 0; mi < 4; ++mi) {
        #pragma unroll
        for (int ni = 0; ni < 4; ++ni) {
            #pragma unroll
            for (int r = 0; r < 4; ++r) {
                int row = R0 + wm + mi * 16 + orow + r;
                int col = J0 + wn + ni * 16 + fr;
                if (row < MT && col < NLON)
                    out[(size_t)row * NLON + col] = acc[mi][ni][r];
            }
        }
    }
}

// ---------------------------------------------------------------------------
// Workspace layout (total 67,371,264 B — proven available):
//   region A [0, 34,009,088):  xT (33,269,760 B)  then interT (34,009,088 B)
//   region B [34,009,088, 67,371,264):  interQ (33,362,176 B) then W
// ---------------------------------------------------------------------------
extern "C" void kernel_launch(void* const* d_in, const int* in_sizes, int n_in,
                              void* d_out, int out_size, void* d_ws, size_t ws_size,
                              hipStream_t stream)
{
    const float* x    = (const float*)d_in[0];
    const float* dpct = (const float*)d_in[1];
    float* out        = (float*)d_out;

    char* ws = (char*)d_ws;
    __hip_bfloat16* xT     = (__hip_bfloat16*)ws;
    __hip_bfloat16* interT = (__hip_bfloat16*)ws;
    __hip_bfloat16* interQ = (__hip_bfloat16*)(ws + 34009088);
    __hip_bfloat16* Wt     = (__hip_bfloat16*)(ws + 34009088);

    dim3 gp(12, 6, 64);
    sht_prep_x<<<gp, 256, 0, stream>>>(x, xT);

    dim3 g1(MMAX, 4);
    sht_gemm1<<<g1, 256, 0, stream>>>(dpct, xT, interQ);

    dim3 gt(MT / 64, 12);
    sht_transpose<<<gt, 256, 0, stream>>>(interQ, interT);

    sht_make_w<<<(NP * KP) / 256, 256, 0, stream>>>(Wt);

    dim3 gg((MT + BM - 1) / BM, NP / BN);
    sht_gemm<<<gg, 256, 0, stream>>>(interT, Wt, out);
}